// Round 5
// baseline (1675.026 us; speedup 1.0000x reference)
//
#include <hip/hip_runtime.h>
#include <hip/hip_fp16.h>

#define DD 64     // feature dim
#define GG 64     // graphs per batch
#define CHUNK 16  // nodes per fine bucket (one wave per bucket in k_agg)
#define PBITS 9   // 512 nodes per coarse partition
#define PSZ 512
#define EPB 8192  // edges per k_part1 block (512 thr x 16)

typedef _Float16 half8 __attribute__((ext_vector_type(8)));
typedef float floatx4 __attribute__((ext_vector_type(4)));

// ---------------- degree count + per-partition edge count ----------------
__global__ __launch_bounds__(256) void k_count(const int* __restrict__ dst, int E,
                                               int* __restrict__ degI,
                                               int* __restrict__ pcnt) {
    __shared__ int h[256];
    if (threadIdx.x < 256) h[threadIdx.x] = 0;
    __syncthreads();
    int i = blockIdx.x * 256 + threadIdx.x;
    if (i < E) {
        int d = dst[i];
        atomicAdd(&degI[d], 1);
        atomicAdd(&h[d >> PBITS], 1);
    }
    __syncthreads();
    if (threadIdx.x < 256 && h[threadIdx.x]) atomicAdd(&pcnt[threadIdx.x], h[threadIdx.x]);
}

// dis = rsqrt(deg + 1)
__global__ __launch_bounds__(256) void k_dis(const int* __restrict__ degI, int N,
                                             float* __restrict__ disv) {
    int i = blockIdx.x * 256 + threadIdx.x;
    if (i < N) disv[i] = rsqrtf((float)(degI[i] + 1));
}

// ---------------- nodes-per-graph counts ----------------
__global__ __launch_bounds__(256) void k_count_batch(const int* __restrict__ batch, int N,
                                                     int* __restrict__ cntI) {
    __shared__ int h[GG];
    if (threadIdx.x < GG) h[threadIdx.x] = 0;
    __syncthreads();
    int i = blockIdx.x * 256 + threadIdx.x;
    if (i < N) atomicAdd(&h[batch[i]], 1);
    __syncthreads();
    if (threadIdx.x < GG) {
        int v = h[threadIdx.x];
        if (v) atomicAdd(&cntI[threadIdx.x], v);
    }
}

// ---------------- tiny serial scan over partitions ----------------
__global__ void k_pscan(const int* __restrict__ pcnt, int* __restrict__ poffs,
                        int* __restrict__ pcur, int* __restrict__ foffs,
                        int npart, int nfine, int E) {
    if (threadIdx.x == 0 && blockIdx.x == 0) {
        int run = 0;
        for (int p = 0; p < npart; ++p) {
            poffs[p] = run;
            pcur[p]  = run;
            run += pcnt[p];
        }
        poffs[npart] = run;   // == E
        foffs[nfine] = E;
    }
}

// ---------------- coarse sorted scatter (LDS counting sort per 8192 edges) ----
// word = src (17b) | (dst & 511) << 17
__global__ __launch_bounds__(512) void k_part1(const int* __restrict__ src,
                                               const int* __restrict__ dst, int E,
                                               int* __restrict__ pcur,
                                               unsigned* __restrict__ pairs1) {
    __shared__ unsigned stage[EPB];
    __shared__ unsigned char sbin[EPB];
    __shared__ int hist[256], binS[256], cur[256], gbase[256];
    int t = threadIdx.x;
    int base = blockIdx.x * EPB;
    int n = min(EPB, E - base);

    if (t < 256) hist[t] = 0;
    __syncthreads();
    // pass A: histogram by partition
    for (int k = 0; k < EPB / 512; ++k) {
        int s = t + k * 512;
        if (s < n) atomicAdd(&hist[dst[base + s] >> PBITS], 1);
    }
    __syncthreads();
    int cnt = (t < 256) ? hist[t] : 0;
    // Hillis-Steele inclusive scan over hist[0..255]
    for (int off = 1; off < 256; off <<= 1) {
        int v = 0;
        if (t >= off && t < 256) v = hist[t - off];
        __syncthreads();
        if (t < 256) hist[t] += v;
        __syncthreads();
    }
    if (t < 256) {
        int excl = hist[t] - cnt;
        binS[t] = excl;
        cur[t]  = excl;
        if (cnt > 0) gbase[t] = atomicAdd(&pcur[t], cnt);
    }
    __syncthreads();
    // pass B: scatter into LDS, sorted by partition
    for (int k = 0; k < EPB / 512; ++k) {
        int s = t + k * 512;
        if (s < n) {
            int d = dst[base + s];
            int p = d >> PBITS;
            unsigned w = (unsigned)src[base + s] | ((unsigned)(d & (PSZ - 1)) << 17);
            int r = atomicAdd(&cur[p], 1);
            stage[r] = w;
            sbin[r]  = (unsigned char)p;
        }
    }
    __syncthreads();
    // flush: consecutive slots in a bin -> consecutive global addresses
    for (int k = 0; k < EPB / 512; ++k) {
        int s = t + k * 512;
        if (s < n) {
            int p = sbin[s];
            pairs1[gbase[p] + (s - binS[p])] = stage[s];
        }
    }
}

// ---------------- refine: sort each partition region by 16-node fine bucket ----
__global__ __launch_bounds__(256) void k_part2(const unsigned* __restrict__ pairs1,
                                               const int* __restrict__ poffs,
                                               unsigned* __restrict__ pairs2,
                                               int* __restrict__ foffs) {
    int p  = blockIdx.x;
    int pb = poffs[p], pe = poffs[p + 1];
    int len = pe - pb;
    __shared__ int h[32], c[32];
    int t = threadIdx.x;
    if (t < 32) h[t] = 0;
    __syncthreads();
    for (int s = t; s < len; s += 256)
        atomicAdd(&h[(pairs1[pb + s] >> 21) & 31], 1);
    __syncthreads();
    if (t == 0) {
        int run = 0;
        for (int f = 0; f < 32; ++f) {
            c[f] = run;
            run += h[f];
        }
    }
    __syncthreads();
    if (t < 32) {
        foffs[p * 32 + t] = pb + c[t];
        h[t] = c[t];   // reuse as cursor
    }
    __syncthreads();
    for (int s = t; s < len; s += 256) {
        unsigned w = pairs1[pb + s];
        int r = atomicAdd(&h[(w >> 21) & 31], 1);
        pairs2[pb + r] = w;
    }
}

// ---------------- g = fp16((x @ W) * dis[row])  — MFMA ----------------
__global__ __launch_bounds__(256) void k_gemm(const float* __restrict__ x,
                                              const float* __restrict__ W,
                                              const float* __restrict__ disv,
                                              __half* __restrict__ g, int N) {
    int lane = threadIdx.x & 63;
    int wave = (blockIdx.x * 256 + threadIdx.x) >> 6;
    int nw   = (gridDim.x * 256) >> 6;
    int col  = lane & 15;
    int krow = (lane >> 4) * 8;

    half8 bf[2][4];
#pragma unroll
    for (int s = 0; s < 2; ++s)
#pragma unroll
        for (int n = 0; n < 4; ++n)
#pragma unroll
            for (int e = 0; e < 8; ++e)
                bf[s][n][e] = (_Float16)W[(size_t)(krow + e + s * 32) * DD + n * 16 + col];

    int nch = (N + 15) >> 4;
    for (int c = wave; c < nch; c += nw) {
        int base = c * 16;
        int arow = base + (lane & 15);
        const float* xr = x + (size_t)min(arow, N - 1) * DD + krow;
        half8 af[2];
#pragma unroll
        for (int s = 0; s < 2; ++s) {
            float4 lo = *(const float4*)(xr + s * 32);
            float4 hi = *(const float4*)(xr + s * 32 + 4);
            af[s][0] = (_Float16)lo.x; af[s][1] = (_Float16)lo.y;
            af[s][2] = (_Float16)lo.z; af[s][3] = (_Float16)lo.w;
            af[s][4] = (_Float16)hi.x; af[s][5] = (_Float16)hi.y;
            af[s][6] = (_Float16)hi.z; af[s][7] = (_Float16)hi.w;
        }
        floatx4 acc[4] = {{0.f, 0.f, 0.f, 0.f}, {0.f, 0.f, 0.f, 0.f},
                          {0.f, 0.f, 0.f, 0.f}, {0.f, 0.f, 0.f, 0.f}};
#pragma unroll
        for (int s = 0; s < 2; ++s)
#pragma unroll
            for (int n = 0; n < 4; ++n)
                acc[n] = __builtin_amdgcn_mfma_f32_16x16x32_f16(af[s], bf[s][n],
                                                                acc[n], 0, 0, 0);
#pragma unroll
        for (int j = 0; j < 4; ++j) {
            int rr = base + (lane >> 4) * 4 + j;
            if (rr < N) {
                float dv = disv[rr];
#pragma unroll
                for (int n = 0; n < 4; ++n)
                    g[(size_t)rr * DD + n * 16 + col] = __float2half(acc[n][j] * dv);
            }
        }
    }
}

// ---------------- fused aggregate + finalize + pooling ----------------
// acc LDS swizzle: element (local, dim) stored at local*64 + (dim ^ (local<<2))
__global__ __launch_bounds__(256) void k_agg(const unsigned* __restrict__ pairs2,
                                             const int* __restrict__ foffs,
                                             const __half* __restrict__ g,
                                             const float* __restrict__ disv,
                                             const float* __restrict__ b,
                                             const int* __restrict__ batch,
                                             float* __restrict__ xout,
                                             float* __restrict__ gacc, int N) {
    __shared__ float acc_s[4][CHUNK * DD];
    int lane = threadIdx.x & 63;
    int w    = threadIdx.x >> 6;
    float* acc = acc_s[w];
    int l16 = lane & 15;
    int g4  = lane >> 4;
    int wave = (blockIdx.x * 256 + threadIdx.x) >> 6;
    int nw   = (gridDim.x * 256) >> 6;
    int NB   = (N + CHUNK - 1) / CHUNK;
    float bj = b[lane];
    for (int bu = wave; bu < NB; bu += nw) {
        int nbase  = bu * CHUNK;
        int nend   = min(nbase + CHUNK, N);
        int bstart = foffs[bu];
        int bend   = foffs[bu + 1];
#pragma unroll
        for (int t = 0; t < CHUNK; ++t) acc[t * DD + lane] = 0.f;
        for (int k = bstart; k < bend; k += 64) {
            int kk = min(bend - k, 64);
            unsigned pk = (lane < kk) ? pairs2[k + lane] : 0u;
            int j = 0;
            for (; j + 3 < kk; j += 4) {
                unsigned ww = __shfl(pk, j + g4);
                int srcn = (int)(ww & 0x1FFFFu);
                int loc  = (int)((ww >> 17) & 15u);
                uint2 rv = *(const uint2*)((const char*)g + ((size_t)srcn * 128 + l16 * 8));
                float2 f0 = __half22float2(*(const __half2*)&rv.x);
                float2 f1 = __half22float2(*(const __half2*)&rv.y);
                int bidx = loc * DD + ((4 * l16) ^ (loc << 2));
                atomicAdd(&acc[bidx + 0], f0.x);
                atomicAdd(&acc[bidx + 1], f0.y);
                atomicAdd(&acc[bidx + 2], f1.x);
                atomicAdd(&acc[bidx + 3], f1.y);
            }
            for (; j < kk; ++j) {
                unsigned ww = __shfl(pk, j);
                int srcn = (int)(ww & 0x1FFFFu);
                int loc  = (int)((ww >> 17) & 15u);
                float v = __half2float(g[(size_t)srcn * DD + lane]);
                atomicAdd(&acc[loc * DD + (lane ^ (loc << 2))], v);
            }
        }
        __builtin_amdgcn_s_waitcnt(0);  // ensure own ds atomics visible (same wave anyway)
        // finalize 16 nodes + fused pooling (batch is sorted)
        float vmax = 0.f, vsum = 0.f;
        int curg = batch[nbase];
        for (int i = nbase; i < nend; ++i) {
            int loc = i - nbase;
            float self = __half2float(g[(size_t)i * DD + lane]);
            float v = disv[i] * (acc[loc * DD + (lane ^ (loc << 2))] + self) + bj;
            v = fmaxf(v, 0.f);
            xout[(size_t)i * DD + lane] = v;
            int gid = batch[i];
            if (gid != curg) {
                atomicMax((unsigned*)&gacc[curg * 2 * DD + lane], __float_as_uint(vmax));
                atomicAdd(&gacc[curg * 2 * DD + DD + lane], vsum);
                vmax = 0.f; vsum = 0.f; curg = gid;
            }
            vmax = fmaxf(vmax, v);
            vsum += v;
        }
        atomicMax((unsigned*)&gacc[curg * 2 * DD + lane], __float_as_uint(vmax));
        atomicAdd(&gacc[curg * 2 * DD + DD + lane], vsum);
    }
}

// ---------------- fold per-layer pool into running total; clear gacc ----------------
__global__ __launch_bounds__(256) void k_pool(float* __restrict__ gacc,
                                              float* __restrict__ gtot,
                                              const int* __restrict__ cntI) {
    int i = blockIdx.x * 256 + threadIdx.x;
    if (i < GG * 2 * DD) {
        int gidx = i >> 7;
        int j    = i & 127;
        float v  = gacc[i];
        if (j >= DD) v = v / (float)cntI[gidx];
        gtot[i] += v;
        gacc[i] = 0.f;
    }
}

__global__ __launch_bounds__(256) void k_copy(const float* __restrict__ srcp,
                                              float* __restrict__ dstp, int n) {
    int i = blockIdx.x * 256 + threadIdx.x;
    if (i < n) dstp[i] = srcp[i];
}

extern "C" void kernel_launch(void* const* d_in, const int* in_sizes, int n_in,
                              void* d_out, int out_size, void* d_ws, size_t ws_size,
                              hipStream_t stream) {
    const float* x     = (const float*)d_in[0];
    const int*   ei    = (const int*)d_in[1];
    const int*   batch = (const int*)d_in[2];

    int N = in_sizes[0] / DD;
    int E = in_sizes[1] / 2;
    const int* src = ei;
    const int* dst = ei + E;

    size_t nd  = (size_t)N * DD;
    int NPART  = (N + PSZ - 1) >> PBITS;
    int NB     = (N + CHUNK - 1) / CHUNK;
    int NF     = NPART * 32;

    float*    ws    = (float*)d_ws;
    float*    bufX  = ws;                           // N*DD f32
    __half*   bufG  = (__half*)(ws + nd);           // N*DD fp16
    float*    disv  = ws + nd + nd / 2;             // N
    float*    gacc  = disv + N;                     // GG*2*DD
    float*    gtot  = gacc + GG * 2 * DD;           // GG*2*DD
    int*      cntI  = (int*)(gtot + GG * 2 * DD);   // GG
    int*      degI  = cntI + GG;                    // N
    int*      pcnt  = degI + N;                     // 256
    int*      poffs = pcnt + 256;                   // NPART+1
    int*      pcur  = poffs + NPART + 1;            // 256
    int*      foffs = pcur + 256;                   // NF+1
    unsigned* pairs1 = (unsigned*)(foffs + NF + 1); // E
    unsigned* pairs2 = pairs1 + E;                  // E

    hipMemsetAsync(degI, 0, (size_t)N * sizeof(int), stream);
    hipMemsetAsync(pcnt, 0, 256 * sizeof(int), stream);
    hipMemsetAsync(gacc, 0, (size_t)GG * 2 * DD * sizeof(float), stream);
    hipMemsetAsync(gtot, 0, (size_t)GG * 2 * DD * sizeof(float), stream);
    hipMemsetAsync(cntI, 0, (size_t)GG * sizeof(int), stream);

    k_count<<<(E + 255) / 256, 256, 0, stream>>>(dst, E, degI, pcnt);
    k_dis<<<(N + 255) / 256, 256, 0, stream>>>(degI, N, disv);
    k_count_batch<<<(N + 255) / 256, 256, 0, stream>>>(batch, N, cntI);
    k_pscan<<<1, 64, 0, stream>>>(pcnt, poffs, pcur, foffs, NPART, NF, E);
    k_part1<<<(E + EPB - 1) / EPB, 512, 0, stream>>>(src, dst, E, pcur, pairs1);
    k_part2<<<NPART, 256, 0, stream>>>(pairs1, poffs, pairs2, foffs);

    const float* xin = x;
    for (int l = 0; l < 3; ++l) {
        const float* W = (const float*)d_in[3 + 2 * l];
        const float* b = (const float*)d_in[4 + 2 * l];
        k_gemm<<<400, 256, 0, stream>>>(xin, W, disv, bufG, N);
        float* xout = (l == 2) ? (float*)d_out : bufX;
        k_agg<<<(NB + 3) / 4, 256, 0, stream>>>(pairs2, foffs, bufG, disv, b, batch,
                                                xout, gacc, N);
        k_pool<<<(GG * 2 * DD + 255) / 256, 256, 0, stream>>>(gacc, gtot, cntI);
        xin = bufX;
    }
    k_copy<<<(GG * 2 * DD + 255) / 256, 256, 0, stream>>>(gtot, (float*)d_out + nd,
                                                          GG * 2 * DD);
}

// Round 6
// 563.397 us; speedup vs baseline: 2.9731x; 2.9731x over previous
//
#include <hip/hip_runtime.h>
#include <hip/hip_fp16.h>

#define DD 64     // feature dim
#define GG 64     // graphs per batch
#define CHUNK 16  // nodes per fine bucket (one wave per bucket in k_agg)
#define PBITS 9   // 512 nodes per coarse partition
#define PSZ 512
#define EPB 8192  // edges per k_part1 block (512 thr x 16)

typedef _Float16 half8 __attribute__((ext_vector_type(8)));
typedef float floatx4 __attribute__((ext_vector_type(4)));

// ---------------- degree count + per-partition edge count ----------------
__global__ __launch_bounds__(256) void k_count(const int* __restrict__ dst, int E,
                                               int* __restrict__ degI,
                                               int* __restrict__ pcnt) {
    __shared__ int h[256];
    if (threadIdx.x < 256) h[threadIdx.x] = 0;
    __syncthreads();
    int i = blockIdx.x * 256 + threadIdx.x;
    if (i < E) {
        int d = dst[i];
        atomicAdd(&degI[d], 1);
        atomicAdd(&h[d >> PBITS], 1);
    }
    __syncthreads();
    if (threadIdx.x < 256 && h[threadIdx.x]) atomicAdd(&pcnt[threadIdx.x], h[threadIdx.x]);
}

// dis = rsqrt(deg + 1)
__global__ __launch_bounds__(256) void k_dis(const int* __restrict__ degI, int N,
                                             float* __restrict__ disv) {
    int i = blockIdx.x * 256 + threadIdx.x;
    if (i < N) disv[i] = rsqrtf((float)(degI[i] + 1));
}

// ---------------- nodes-per-graph counts ----------------
__global__ __launch_bounds__(256) void k_count_batch(const int* __restrict__ batch, int N,
                                                     int* __restrict__ cntI) {
    __shared__ int h[GG];
    if (threadIdx.x < GG) h[threadIdx.x] = 0;
    __syncthreads();
    int i = blockIdx.x * 256 + threadIdx.x;
    if (i < N) atomicAdd(&h[batch[i]], 1);
    __syncthreads();
    if (threadIdx.x < GG) {
        int v = h[threadIdx.x];
        if (v) atomicAdd(&cntI[threadIdx.x], v);
    }
}

// ---------------- parallel scan over partitions (npart <= 256) ----------------
__global__ __launch_bounds__(256) void k_pscan(const int* __restrict__ pcnt,
                                               int* __restrict__ poffs,
                                               int* __restrict__ pcur,
                                               int* __restrict__ foffs,
                                               int npart, int nfine, int E) {
    __shared__ int sh[256];
    int t = threadIdx.x;
    int v = (t < npart) ? pcnt[t] : 0;
    sh[t] = v;
    __syncthreads();
    for (int off = 1; off < 256; off <<= 1) {
        int u = (t >= off) ? sh[t - off] : 0;
        __syncthreads();
        sh[t] += u;
        __syncthreads();
    }
    int excl = sh[t] - v;
    if (t < npart) {
        poffs[t] = excl;
        pcur[t]  = excl;
    }
    if (t == 0) {
        poffs[npart] = sh[255];
        foffs[nfine] = E;
    }
}

// ---------------- coarse sorted scatter (LDS counting sort per 8192 edges) ----
// word = src (17b) | (dst & 511) << 17
__global__ __launch_bounds__(512) void k_part1(const int* __restrict__ src,
                                               const int* __restrict__ dst, int E,
                                               int* __restrict__ pcur,
                                               unsigned* __restrict__ pairs1) {
    __shared__ unsigned stage[EPB];
    __shared__ unsigned char sbin[EPB];
    __shared__ int hist[256], binS[256], cur[256], gbase[256];
    int t = threadIdx.x;
    int base = blockIdx.x * EPB;
    int n = min(EPB, E - base);

    if (t < 256) hist[t] = 0;
    __syncthreads();
    for (int k = 0; k < EPB / 512; ++k) {
        int s = t + k * 512;
        if (s < n) atomicAdd(&hist[dst[base + s] >> PBITS], 1);
    }
    __syncthreads();
    int cnt = (t < 256) ? hist[t] : 0;
    for (int off = 1; off < 256; off <<= 1) {
        int v = 0;
        if (t >= off && t < 256) v = hist[t - off];
        __syncthreads();
        if (t < 256) hist[t] += v;
        __syncthreads();
    }
    if (t < 256) {
        int excl = hist[t] - cnt;
        binS[t] = excl;
        cur[t]  = excl;
        if (cnt > 0) gbase[t] = atomicAdd(&pcur[t], cnt);
    }
    __syncthreads();
    for (int k = 0; k < EPB / 512; ++k) {
        int s = t + k * 512;
        if (s < n) {
            int d = dst[base + s];
            int p = d >> PBITS;
            unsigned w = (unsigned)src[base + s] | ((unsigned)(d & (PSZ - 1)) << 17);
            int r = atomicAdd(&cur[p], 1);
            stage[r] = w;
            sbin[r]  = (unsigned char)p;
        }
    }
    __syncthreads();
    for (int k = 0; k < EPB / 512; ++k) {
        int s = t + k * 512;
        if (s < n) {
            int p = sbin[s];
            pairs1[gbase[p] + (s - binS[p])] = stage[s];
        }
    }
}

// ---------------- refine: sort each partition region by 16-node fine bucket ----
__global__ __launch_bounds__(256) void k_part2(const unsigned* __restrict__ pairs1,
                                               const int* __restrict__ poffs,
                                               unsigned* __restrict__ pairs2,
                                               int* __restrict__ foffs) {
    int p  = blockIdx.x;
    int pb = poffs[p], pe = poffs[p + 1];
    int len = pe - pb;
    __shared__ int h[32], c[32];
    int t = threadIdx.x;
    if (t < 32) h[t] = 0;
    __syncthreads();
    for (int s = t; s < len; s += 256)
        atomicAdd(&h[(pairs1[pb + s] >> 21) & 31], 1);
    __syncthreads();
    if (t == 0) {
        int run = 0;
        for (int f = 0; f < 32; ++f) {
            c[f] = run;
            run += h[f];
        }
    }
    __syncthreads();
    if (t < 32) {
        foffs[p * 32 + t] = pb + c[t];
        h[t] = c[t];
    }
    __syncthreads();
    for (int s = t; s < len; s += 256) {
        unsigned w = pairs1[pb + s];
        int r = atomicAdd(&h[(w >> 21) & 31], 1);
        pairs2[pb + r] = w;
    }
}

// ---------------- g = fp16((x @ W) * dis[row])  — MFMA ----------------
__global__ __launch_bounds__(256) void k_gemm(const float* __restrict__ x,
                                              const float* __restrict__ W,
                                              const float* __restrict__ disv,
                                              __half* __restrict__ g, int N) {
    int lane = threadIdx.x & 63;
    int wave = (blockIdx.x * 256 + threadIdx.x) >> 6;
    int nw   = (gridDim.x * 256) >> 6;
    int col  = lane & 15;
    int krow = (lane >> 4) * 8;

    half8 bf[2][4];
#pragma unroll
    for (int s = 0; s < 2; ++s)
#pragma unroll
        for (int n = 0; n < 4; ++n)
#pragma unroll
            for (int e = 0; e < 8; ++e)
                bf[s][n][e] = (_Float16)W[(size_t)(krow + e + s * 32) * DD + n * 16 + col];

    int nch = (N + 15) >> 4;
    for (int c = wave; c < nch; c += nw) {
        int base = c * 16;
        int arow = base + (lane & 15);
        const float* xr = x + (size_t)min(arow, N - 1) * DD + krow;
        half8 af[2];
#pragma unroll
        for (int s = 0; s < 2; ++s) {
            float4 lo = *(const float4*)(xr + s * 32);
            float4 hi = *(const float4*)(xr + s * 32 + 4);
            af[s][0] = (_Float16)lo.x; af[s][1] = (_Float16)lo.y;
            af[s][2] = (_Float16)lo.z; af[s][3] = (_Float16)lo.w;
            af[s][4] = (_Float16)hi.x; af[s][5] = (_Float16)hi.y;
            af[s][6] = (_Float16)hi.z; af[s][7] = (_Float16)hi.w;
        }
        floatx4 acc[4] = {{0.f, 0.f, 0.f, 0.f}, {0.f, 0.f, 0.f, 0.f},
                          {0.f, 0.f, 0.f, 0.f}, {0.f, 0.f, 0.f, 0.f}};
#pragma unroll
        for (int s = 0; s < 2; ++s)
#pragma unroll
            for (int n = 0; n < 4; ++n)
                acc[n] = __builtin_amdgcn_mfma_f32_16x16x32_f16(af[s], bf[s][n],
                                                                acc[n], 0, 0, 0);
#pragma unroll
        for (int j = 0; j < 4; ++j) {
            int rr = base + (lane >> 4) * 4 + j;
            if (rr < N) {
                float dv = disv[rr];
#pragma unroll
                for (int n = 0; n < 4; ++n)
                    g[(size_t)rr * DD + n * 16 + col] = __float2half(acc[n][j] * dv);
            }
        }
    }
}

// ---------------- fused aggregate + finalize + pooling ----------------
// 2 waves/block; each wave owns 4 accumulator copies (one per 16-lane group).
// Quad of 4 edges processed per step, group g handles edge j+g in its own copy:
// no races, plain ds_read_b128/add/ds_write_b128, no atomics.
__global__ __launch_bounds__(128) void k_agg(const unsigned* __restrict__ pairs2,
                                             const int* __restrict__ foffs,
                                             const __half* __restrict__ g,
                                             const float* __restrict__ disv,
                                             const float* __restrict__ b,
                                             const int* __restrict__ batch,
                                             float* __restrict__ xout,
                                             float* __restrict__ gacc, int N) {
    __shared__ float acc_s[2][4][CHUNK * DD];   // 32 KB/block
    int lane = threadIdx.x & 63;
    int w    = threadIdx.x >> 6;
    int l16  = lane & 15;
    int g4   = lane >> 4;
    float* accg = acc_s[w][g4];
    int wave = (blockIdx.x * 128 + threadIdx.x) >> 6;
    int nw   = (gridDim.x * 128) >> 6;
    int NB   = (N + CHUNK - 1) / CHUNK;
    float bj = b[lane];
    const char* gb = (const char*)g;
    for (int bu = wave; bu < NB; bu += nw) {
        int nbase  = bu * CHUNK;
        int nend   = min(nbase + CHUNK, N);
        int bstart = foffs[bu];
        int bend   = foffs[bu + 1];
#pragma unroll
        for (int t = 0; t < CHUNK; ++t)
            *(float4*)&accg[t * DD + l16 * 4] = float4{0.f, 0.f, 0.f, 0.f};
        for (int k = bstart; k < bend; k += 64) {
            int kk = min(bend - k, 64);
            unsigned pk = (lane < kk) ? pairs2[k + lane] : 0u;
            for (int j = 0; j < kk; j += 4) {
                int idx = j + g4;
                unsigned ww = __shfl(pk, idx);
                if (idx < kk) {
                    int srcn = (int)(ww & 0x1FFFFu);
                    int loc  = (int)((ww >> 17) & 15u);
                    uint2 rv = *(const uint2*)(gb + ((size_t)srcn * 128 + l16 * 8));
                    float2 f0 = __half22float2(*(const __half2*)&rv.x);
                    float2 f1 = __half22float2(*(const __half2*)&rv.y);
                    float4* p = (float4*)&accg[loc * DD + l16 * 4];
                    float4 o = *p;
                    o.x += f0.x; o.y += f0.y; o.z += f1.x; o.w += f1.y;
                    *p = o;
                }
            }
        }
        // finalize 16 nodes + fused pooling (batch is sorted)
        float vmax = 0.f, vsum = 0.f;
        int curg = batch[nbase];
        for (int i = nbase; i < nend; ++i) {
            int loc = i - nbase;
            float a = acc_s[w][0][loc * DD + lane] + acc_s[w][1][loc * DD + lane] +
                      acc_s[w][2][loc * DD + lane] + acc_s[w][3][loc * DD + lane];
            float self = __half2float(g[(size_t)i * DD + lane]);
            float v = disv[i] * (a + self) + bj;
            v = fmaxf(v, 0.f);
            xout[(size_t)i * DD + lane] = v;
            int gid = batch[i];
            if (gid != curg) {
                atomicMax((unsigned*)&gacc[curg * 2 * DD + lane], __float_as_uint(vmax));
                atomicAdd(&gacc[curg * 2 * DD + DD + lane], vsum);
                vmax = 0.f; vsum = 0.f; curg = gid;
            }
            vmax = fmaxf(vmax, v);
            vsum += v;
        }
        atomicMax((unsigned*)&gacc[curg * 2 * DD + lane], __float_as_uint(vmax));
        atomicAdd(&gacc[curg * 2 * DD + DD + lane], vsum);
    }
}

// ---------------- fold per-layer pool into running total; clear gacc ----------------
__global__ __launch_bounds__(256) void k_pool(float* __restrict__ gacc,
                                              float* __restrict__ gtot,
                                              const int* __restrict__ cntI) {
    int i = blockIdx.x * 256 + threadIdx.x;
    if (i < GG * 2 * DD) {
        int gidx = i >> 7;
        int j    = i & 127;
        float v  = gacc[i];
        if (j >= DD) v = v / (float)cntI[gidx];
        gtot[i] += v;
        gacc[i] = 0.f;
    }
}

__global__ __launch_bounds__(256) void k_copy(const float* __restrict__ srcp,
                                              float* __restrict__ dstp, int n) {
    int i = blockIdx.x * 256 + threadIdx.x;
    if (i < n) dstp[i] = srcp[i];
}

extern "C" void kernel_launch(void* const* d_in, const int* in_sizes, int n_in,
                              void* d_out, int out_size, void* d_ws, size_t ws_size,
                              hipStream_t stream) {
    const float* x     = (const float*)d_in[0];
    const int*   ei    = (const int*)d_in[1];
    const int*   batch = (const int*)d_in[2];

    int N = in_sizes[0] / DD;
    int E = in_sizes[1] / 2;
    const int* src = ei;
    const int* dst = ei + E;

    size_t nd  = (size_t)N * DD;
    int NPART  = (N + PSZ - 1) >> PBITS;
    int NB     = (N + CHUNK - 1) / CHUNK;
    int NF     = NPART * 32;

    float*    ws    = (float*)d_ws;
    float*    bufX  = ws;                           // N*DD f32
    __half*   bufG  = (__half*)(ws + nd);           // N*DD fp16
    float*    disv  = ws + nd + nd / 2;             // N
    float*    gacc  = disv + N;                     // GG*2*DD
    float*    gtot  = gacc + GG * 2 * DD;           // GG*2*DD
    int*      cntI  = (int*)(gtot + GG * 2 * DD);   // GG
    int*      degI  = cntI + GG;                    // N
    int*      pcnt  = degI + N;                     // 256
    int*      poffs = pcnt + 256;                   // NPART+1
    int*      pcur  = poffs + NPART + 1;            // 256
    int*      foffs = pcur + 256;                   // NF+1
    unsigned* pairs1 = (unsigned*)(foffs + NF + 1); // E
    unsigned* pairs2 = pairs1 + E;                  // E

    hipMemsetAsync(degI, 0, (size_t)N * sizeof(int), stream);
    hipMemsetAsync(pcnt, 0, 256 * sizeof(int), stream);
    hipMemsetAsync(gacc, 0, (size_t)GG * 2 * DD * sizeof(float), stream);
    hipMemsetAsync(gtot, 0, (size_t)GG * 2 * DD * sizeof(float), stream);
    hipMemsetAsync(cntI, 0, (size_t)GG * sizeof(int), stream);

    k_count<<<(E + 255) / 256, 256, 0, stream>>>(dst, E, degI, pcnt);
    k_dis<<<(N + 255) / 256, 256, 0, stream>>>(degI, N, disv);
    k_count_batch<<<(N + 255) / 256, 256, 0, stream>>>(batch, N, cntI);
    k_pscan<<<1, 256, 0, stream>>>(pcnt, poffs, pcur, foffs, NPART, NF, E);
    k_part1<<<(E + EPB - 1) / EPB, 512, 0, stream>>>(src, dst, E, pcur, pairs1);
    k_part2<<<NPART, 256, 0, stream>>>(pairs1, poffs, pairs2, foffs);

    const float* xin = x;
    for (int l = 0; l < 3; ++l) {
        const float* W = (const float*)d_in[3 + 2 * l];
        const float* b = (const float*)d_in[4 + 2 * l];
        k_gemm<<<400, 256, 0, stream>>>(xin, W, disv, bufG, N);
        float* xout = (l == 2) ? (float*)d_out : bufX;
        k_agg<<<(NB + 1) / 2, 128, 0, stream>>>(pairs2, foffs, bufG, disv, b, batch,
                                                xout, gacc, N);
        k_pool<<<(GG * 2 * DD + 255) / 256, 256, 0, stream>>>(gacc, gtot, cntI);
        xin = bufX;
    }
    k_copy<<<(GG * 2 * DD + 255) / 256, 256, 0, stream>>>(gtot, (float*)d_out + nd,
                                                          GG * 2 * DD);
}

// Round 7
// 349.684 us; speedup vs baseline: 4.7901x; 1.6112x over previous
//
#include <hip/hip_runtime.h>
#include <hip/hip_fp16.h>

#define DD 64     // feature dim
#define GG 64     // graphs per batch
#define CHUNK 16  // nodes per wave-chunk in k_agg
#define PBITS 9   // 512 nodes per coarse partition
#define PSZ 512
#define EPB 8192  // edges per histogram/sort block

typedef _Float16 half8 __attribute__((ext_vector_type(8)));
typedef float floatx4 __attribute__((ext_vector_type(4)));

// ---------------- per-block partition histogram (no global atomics) ----------
__global__ __launch_bounds__(512) void k_hist(const int* __restrict__ dst, int E,
                                              int* __restrict__ bcnt) {
    __shared__ int h[256];
    int t = threadIdx.x;
    if (t < 256) h[t] = 0;
    __syncthreads();
    int base = blockIdx.x * EPB;
    int n = min(EPB, E - base);
    for (int k = 0; k < EPB / 512; ++k) {
        int s = t + k * 512;
        if (s < n) atomicAdd(&h[dst[base + s] >> PBITS], 1);
    }
    __syncthreads();
    if (t < 256) bcnt[blockIdx.x * 256 + t] = h[t];
}

// ---------------- scan: bcnt -> per-(block,partition) bases; poffs ----------
__global__ __launch_bounds__(256) void k_scanB(int* __restrict__ bcnt, int nb,
                                               int* __restrict__ poffs,
                                               int* __restrict__ noffs,
                                               int N, int E) {
    __shared__ int sh[256];
    int t = threadIdx.x;
    int run = 0;
    for (int blk = 0; blk < nb; ++blk) {
        int v = bcnt[blk * 256 + t];
        bcnt[blk * 256 + t] = run;
        run += v;
    }
    int tot = run;
    sh[t] = tot;
    __syncthreads();
    for (int off = 1; off < 256; off <<= 1) {
        int u = (t >= off) ? sh[t - off] : 0;
        __syncthreads();
        sh[t] += u;
        __syncthreads();
    }
    int excl = sh[t] - tot;
    poffs[t] = excl;
    if (t == 0) {
        poffs[256] = E;
        noffs[N] = E;
    }
    for (int blk = 0; blk < nb; ++blk)
        bcnt[blk * 256 + t] += excl;
}

// ---------------- nodes-per-graph counts ----------------
__global__ __launch_bounds__(256) void k_count_batch(const int* __restrict__ batch, int N,
                                                     int* __restrict__ cntI) {
    __shared__ int h[GG];
    if (threadIdx.x < GG) h[threadIdx.x] = 0;
    __syncthreads();
    int i = blockIdx.x * 256 + threadIdx.x;
    if (i < N) atomicAdd(&h[batch[i]], 1);
    __syncthreads();
    if (threadIdx.x < GG) {
        int v = h[threadIdx.x];
        if (v) atomicAdd(&cntI[threadIdx.x], v);
    }
}

// ---------------- coarse sorted scatter (LDS counting sort per 8192 edges) ----
// word = src (17b) | (dst & 511) << 17 ; flush bases from bcnt (deterministic)
__global__ __launch_bounds__(512) void k_part1(const int* __restrict__ src,
                                               const int* __restrict__ dst, int E,
                                               const int* __restrict__ bcnt,
                                               unsigned* __restrict__ pairs1) {
    __shared__ unsigned stage[EPB];
    __shared__ unsigned char sbin[EPB];
    __shared__ int hist[256], binS[256], cur[256], gbase[256];
    int t = threadIdx.x;
    int base = blockIdx.x * EPB;
    int n = min(EPB, E - base);

    if (t < 256) {
        hist[t] = 0;
        gbase[t] = bcnt[blockIdx.x * 256 + t];
    }
    __syncthreads();
    for (int k = 0; k < EPB / 512; ++k) {
        int s = t + k * 512;
        if (s < n) atomicAdd(&hist[dst[base + s] >> PBITS], 1);
    }
    __syncthreads();
    int cnt = (t < 256) ? hist[t] : 0;
    for (int off = 1; off < 256; off <<= 1) {
        int v = 0;
        if (t >= off && t < 256) v = hist[t - off];
        __syncthreads();
        if (t < 256) hist[t] += v;
        __syncthreads();
    }
    if (t < 256) {
        int excl = hist[t] - cnt;
        binS[t] = excl;
        cur[t]  = excl;
    }
    __syncthreads();
    for (int k = 0; k < EPB / 512; ++k) {
        int s = t + k * 512;
        if (s < n) {
            int d = dst[base + s];
            int p = d >> PBITS;
            unsigned w = (unsigned)src[base + s] | ((unsigned)(d & (PSZ - 1)) << 17);
            int r = atomicAdd(&cur[p], 1);
            stage[r] = w;
            sbin[r]  = (unsigned char)p;
        }
    }
    __syncthreads();
    for (int k = 0; k < EPB / 512; ++k) {
        int s = t + k * 512;
        if (s < n) {
            int p = sbin[s];
            pairs1[gbase[p] + (s - binS[p])] = stage[s];
        }
    }
}

// ---------------- refine: full per-node sort within partition; emit noffs ----
__global__ __launch_bounds__(256) void k_part2(const unsigned* __restrict__ pairs1,
                                               const int* __restrict__ poffs,
                                               int* __restrict__ pairs2,
                                               int* __restrict__ noffs, int N) {
    int p  = blockIdx.x;
    int pb = poffs[p], pe = poffs[p + 1];
    int len = pe - pb;
    __shared__ int h[PSZ];
    __shared__ int sc[256];
    int t = threadIdx.x;
    h[t] = 0;
    h[t + 256] = 0;
    __syncthreads();
    for (int s = t; s < len; s += 256)
        atomicAdd(&h[(pairs1[pb + s] >> 17) & (PSZ - 1)], 1);
    __syncthreads();
    int a  = h[2 * t];
    int b2 = h[2 * t + 1];
    sc[t] = a + b2;
    __syncthreads();
    for (int off = 1; off < 256; off <<= 1) {
        int u = (t >= off) ? sc[t - off] : 0;
        __syncthreads();
        sc[t] += u;
        __syncthreads();
    }
    int ex = sc[t] - (a + b2);
    int n0 = p * PSZ + 2 * t;
    if (n0 < N)     noffs[n0]     = pb + ex;
    if (n0 + 1 < N) noffs[n0 + 1] = pb + ex + a;
    __syncthreads();
    h[2 * t]     = ex;
    h[2 * t + 1] = ex + a;
    __syncthreads();
    for (int s = t; s < len; s += 256) {
        unsigned w = pairs1[pb + s];
        int r = atomicAdd(&h[(w >> 17) & (PSZ - 1)], 1);
        pairs2[pb + r] = (int)(w & 0x1FFFFu);
    }
}

// ---------------- dis = rsqrt(deg+1), deg from noffs ----------------
__global__ __launch_bounds__(256) void k_dis(const int* __restrict__ noffs, int N,
                                             float* __restrict__ disv) {
    int i = blockIdx.x * 256 + threadIdx.x;
    if (i < N) disv[i] = rsqrtf((float)(noffs[i + 1] - noffs[i] + 1));
}

// ---------------- g = fp16((x @ W) * dis[row])  — MFMA ----------------
__global__ __launch_bounds__(256) void k_gemm(const float* __restrict__ x,
                                              const float* __restrict__ W,
                                              const float* __restrict__ disv,
                                              __half* __restrict__ g, int N) {
    int lane = threadIdx.x & 63;
    int wave = (blockIdx.x * 256 + threadIdx.x) >> 6;
    int nw   = (gridDim.x * 256) >> 6;
    int col  = lane & 15;
    int krow = (lane >> 4) * 8;

    half8 bf[2][4];
#pragma unroll
    for (int s = 0; s < 2; ++s)
#pragma unroll
        for (int n = 0; n < 4; ++n)
#pragma unroll
            for (int e = 0; e < 8; ++e)
                bf[s][n][e] = (_Float16)W[(size_t)(krow + e + s * 32) * DD + n * 16 + col];

    int nch = (N + 15) >> 4;
    for (int c = wave; c < nch; c += nw) {
        int base = c * 16;
        int arow = base + (lane & 15);
        const float* xr = x + (size_t)min(arow, N - 1) * DD + krow;
        half8 af[2];
#pragma unroll
        for (int s = 0; s < 2; ++s) {
            float4 lo = *(const float4*)(xr + s * 32);
            float4 hi = *(const float4*)(xr + s * 32 + 4);
            af[s][0] = (_Float16)lo.x; af[s][1] = (_Float16)lo.y;
            af[s][2] = (_Float16)lo.z; af[s][3] = (_Float16)lo.w;
            af[s][4] = (_Float16)hi.x; af[s][5] = (_Float16)hi.y;
            af[s][6] = (_Float16)hi.z; af[s][7] = (_Float16)hi.w;
        }
        floatx4 acc[4] = {{0.f, 0.f, 0.f, 0.f}, {0.f, 0.f, 0.f, 0.f},
                          {0.f, 0.f, 0.f, 0.f}, {0.f, 0.f, 0.f, 0.f}};
#pragma unroll
        for (int s = 0; s < 2; ++s)
#pragma unroll
            for (int n = 0; n < 4; ++n)
                acc[n] = __builtin_amdgcn_mfma_f32_16x16x32_f16(af[s], bf[s][n],
                                                                acc[n], 0, 0, 0);
#pragma unroll
        for (int j = 0; j < 4; ++j) {
            int rr = base + (lane >> 4) * 4 + j;
            if (rr < N) {
                float dv = disv[rr];
#pragma unroll
                for (int n = 0; n < 4; ++n)
                    g[(size_t)rr * DD + n * 16 + col] = __float2half(acc[n][j] * dv);
            }
        }
    }
}

// ---------------- fused aggregate + finalize + pooling (register acc) --------
// Edges sorted per node (noffs CSR). Each half-wave (32 lanes x uint = one
// 128B fp16 row) accumulates a full feature row in float2 registers; 2 edges
// per wave-load; one shfl_xor(32) combine per node. No LDS.
__global__ __launch_bounds__(256) void k_agg(const int* __restrict__ pairs2,
                                             const int* __restrict__ noffs,
                                             const __half* __restrict__ g,
                                             const float* __restrict__ disv,
                                             const float* __restrict__ bbias,
                                             const int* __restrict__ batch,
                                             float* __restrict__ xout,
                                             float* __restrict__ gacc, int N) {
    int lane = threadIdx.x & 63;
    int half = lane >> 5;
    int l32  = lane & 31;
    int wave = (blockIdx.x * 256 + threadIdx.x) >> 6;
    int nw   = (gridDim.x * 256) >> 6;
    int NB   = (N + CHUNK - 1) / CHUNK;
    float2 bj = {bbias[2 * l32], bbias[2 * l32 + 1]};
    const char* gb = (const char*)g;
    for (int bu = wave; bu < NB; bu += nw) {
        int nbase = bu * CHUNK;
        int nend  = min(nbase + CHUNK, N);
        int nn    = nend - nbase;
        int nf  = noffs[nbase + min(lane, nn)];
        int bch = batch[nbase + min(lane, nn - 1)];
        float2 vmax = {0.f, 0.f}, vsum = {0.f, 0.f};
        int curg = __shfl(bch, 0);
        for (int i = 0; i < nn; ++i) {
            int s0  = __shfl(nf, i);
            int s1  = __shfl(nf, i + 1);
            int cnt = s1 - s0;
            float2 acc = {0.f, 0.f};
            if (half == 0) {   // self-loop row added once
                unsigned su = *(const unsigned*)(gb + ((size_t)(nbase + i) * 128 + l32 * 4));
                acc = __half22float2(*(const __half2*)&su);
            }
            for (int k = 0; k < cnt; k += 64) {
                int kk = min(cnt - k, 64);
                int pk = (lane < kk) ? pairs2[s0 + k + lane] : 0;
                for (int j = 0; j < kk; j += 2) {
                    int idx  = j + half;
                    int sidx = __shfl(pk, idx);
                    if (idx < kk) {
                        unsigned rv = *(const unsigned*)(gb + ((size_t)sidx * 128 + l32 * 4));
                        float2 f = __half22float2(*(const __half2*)&rv);
                        acc.x += f.x;
                        acc.y += f.y;
                    }
                }
            }
            acc.x += __shfl_xor(acc.x, 32);
            acc.y += __shfl_xor(acc.y, 32);
            float dv = disv[nbase + i];
            float2 v;
            v.x = fmaxf(fmaf(dv, acc.x, bj.x), 0.f);
            v.y = fmaxf(fmaf(dv, acc.y, bj.y), 0.f);
            if (half == 0)
                *(float2*)&xout[(size_t)(nbase + i) * DD + 2 * l32] = v;
            int gid = __shfl(bch, i);
            if (gid != curg) {
                if (half == 0) {
                    atomicMax((unsigned*)&gacc[curg * 128 + 2 * l32],
                              __float_as_uint(vmax.x));
                    atomicMax((unsigned*)&gacc[curg * 128 + 2 * l32 + 1],
                              __float_as_uint(vmax.y));
                    atomicAdd(&gacc[curg * 128 + 64 + 2 * l32], vsum.x);
                    atomicAdd(&gacc[curg * 128 + 64 + 2 * l32 + 1], vsum.y);
                }
                vmax = {0.f, 0.f};
                vsum = {0.f, 0.f};
                curg = gid;
            }
            vmax.x = fmaxf(vmax.x, v.x);
            vmax.y = fmaxf(vmax.y, v.y);
            vsum.x += v.x;
            vsum.y += v.y;
        }
        if (half == 0) {
            atomicMax((unsigned*)&gacc[curg * 128 + 2 * l32], __float_as_uint(vmax.x));
            atomicMax((unsigned*)&gacc[curg * 128 + 2 * l32 + 1], __float_as_uint(vmax.y));
            atomicAdd(&gacc[curg * 128 + 64 + 2 * l32], vsum.x);
            atomicAdd(&gacc[curg * 128 + 64 + 2 * l32 + 1], vsum.y);
        }
    }
}

// ---------------- fold per-layer pool into running total; clear gacc ---------
__global__ __launch_bounds__(256) void k_pool(float* __restrict__ gacc,
                                              float* __restrict__ gtot,
                                              const int* __restrict__ cntI) {
    int i = blockIdx.x * 256 + threadIdx.x;
    if (i < GG * 2 * DD) {
        int gidx = i >> 7;
        int j    = i & 127;
        float v  = gacc[i];
        if (j >= DD) v = v / (float)cntI[gidx];
        gtot[i] += v;
        gacc[i] = 0.f;
    }
}

__global__ __launch_bounds__(256) void k_copy(const float* __restrict__ srcp,
                                              float* __restrict__ dstp, int n) {
    int i = blockIdx.x * 256 + threadIdx.x;
    if (i < n) dstp[i] = srcp[i];
}

extern "C" void kernel_launch(void* const* d_in, const int* in_sizes, int n_in,
                              void* d_out, int out_size, void* d_ws, size_t ws_size,
                              hipStream_t stream) {
    const float* x     = (const float*)d_in[0];
    const int*   ei    = (const int*)d_in[1];
    const int*   batch = (const int*)d_in[2];

    int N = in_sizes[0] / DD;
    int E = in_sizes[1] / 2;
    const int* src = ei;
    const int* dst = ei + E;

    size_t nd  = (size_t)N * DD;
    int NPART  = (N + PSZ - 1) >> PBITS;
    int NB     = (N + CHUNK - 1) / CHUNK;
    int nb     = (E + EPB - 1) / EPB;

    float*    ws     = (float*)d_ws;
    float*    bufX   = ws;                            // N*DD f32
    __half*   bufG   = (__half*)(ws + nd);            // N*DD fp16
    float*    disv   = ws + nd + nd / 2;              // N
    float*    gacc   = disv + N;                      // GG*2*DD
    float*    gtot   = gacc + GG * 2 * DD;            // GG*2*DD
    int*      cntI   = (int*)(gtot + GG * 2 * DD);    // GG
    int*      poffs  = cntI + GG;                     // 257
    int*      noffs  = poffs + 257;                   // N+1
    int*      bcnt   = noffs + N + 1;                 // nb*256
    unsigned* pairs1 = (unsigned*)(bcnt + nb * 256);  // E
    int*      pairs2 = (int*)(pairs1 + E);            // E

    hipMemsetAsync(gacc, 0, (size_t)GG * 2 * DD * sizeof(float), stream);
    hipMemsetAsync(gtot, 0, (size_t)GG * 2 * DD * sizeof(float), stream);
    hipMemsetAsync(cntI, 0, (size_t)GG * sizeof(int), stream);

    k_hist<<<nb, 512, 0, stream>>>(dst, E, bcnt);
    k_scanB<<<1, 256, 0, stream>>>(bcnt, nb, poffs, noffs, N, E);
    k_count_batch<<<(N + 255) / 256, 256, 0, stream>>>(batch, N, cntI);
    k_part1<<<nb, 512, 0, stream>>>(src, dst, E, bcnt, pairs1);
    k_part2<<<NPART, 256, 0, stream>>>(pairs1, poffs, pairs2, noffs, N);
    k_dis<<<(N + 255) / 256, 256, 0, stream>>>(noffs, N, disv);

    const float* xin = x;
    for (int l = 0; l < 3; ++l) {
        const float* W = (const float*)d_in[3 + 2 * l];
        const float* b = (const float*)d_in[4 + 2 * l];
        k_gemm<<<400, 256, 0, stream>>>(xin, W, disv, bufG, N);
        float* xout = (l == 2) ? (float*)d_out : bufX;
        k_agg<<<(NB * 64 + 255) / 256, 256, 0, stream>>>(pairs2, noffs, bufG, disv, b,
                                                         batch, xout, gacc, N);
        k_pool<<<(GG * 2 * DD + 255) / 256, 256, 0, stream>>>(gacc, gtot, cntI);
        xin = bufX;
    }
    k_copy<<<(GG * 2 * DD + 255) / 256, 256, 0, stream>>>(gtot, (float*)d_out + nd,
                                                          GG * 2 * DD);
}